// Round 4
// baseline (1157.398 us; speedup 1.0000x reference)
//
#include <hip/hip_runtime.h>

#define N_NODES 50000
#define N_EDGES 1600000
#define IN_CH   256
#define ADP     64
#define EDGE_DIM 32
#define GRP     196     // ceil(50000/256) node groups
#define GCAP    12288   // per-group bucket capacity (mean 8163, sd ~90)
#define EPB_A   2048    // edges per block in k_bucket
#define NB_BUCKET ((N_EDGES + EPB_A - 1) / EPB_A)   // 782
#define NT16    (N_NODES / 16)                      // 3125 node tiles
#define NB_GEMM ((NT16 + 3) / 4)                    // 782

typedef __fp16 h2 __attribute__((ext_vector_type(2)));
typedef _Float16 f16x8 __attribute__((ext_vector_type(8)));
typedef float f32x4 __attribute__((ext_vector_type(4)));
union UH { unsigned int u; h2 h; };

__device__ inline f16x8 cvt8(float4 a, float4 b) {
    union { f16x8 v; h2 h[4]; } r;
    r.h[0] = __builtin_amdgcn_cvt_pkrtz(a.x, a.y);
    r.h[1] = __builtin_amdgcn_cvt_pkrtz(a.z, a.w);
    r.h[2] = __builtin_amdgcn_cvt_pkrtz(b.x, b.y);
    r.h[3] = __builtin_amdgcn_cvt_pkrtz(b.z, b.w);
    return r.v;
}

__device__ inline uint4 pack8(float4 a, float4 b) {
    UH p0, p1, p2, p3;
    p0.h = __builtin_amdgcn_cvt_pkrtz(a.x, a.y);
    p1.h = __builtin_amdgcn_cvt_pkrtz(a.z, a.w);
    p2.h = __builtin_amdgcn_cvt_pkrtz(b.x, b.y);
    p3.h = __builtin_amdgcn_cvt_pkrtz(b.z, b.w);
    return make_uint4(p0.u, p1.u, p2.u, p3.u);
}

// ---------------- K_A: bucket by 256-node group, carrying f16 payload --------
// Streams ea coalesced; writes each edge's 64B f16 row + node-in-group id into
// the group slab at a block-reserved contiguous frontier window.
__global__ __launch_bounds__(256) void k_bucket(const int* __restrict__ ei_src,
                                                const float* __restrict__ ea,
                                                int* __restrict__ gcnt,
                                                _Float16* __restrict__ payload,
                                                unsigned short* __restrict__ nid) {
    __shared__ int cnt[GRP];
    __shared__ int cur[GRP];
    int t = threadIdx.x;
    if (t < GRP) cnt[t] = 0;
    __syncthreads();
    int base = blockIdx.x * EPB_A;
    int s[8];
    #pragma unroll
    for (int k = 0; k < 8; k++) {
        int e = base + k * 256 + t;
        int v = (e < N_EDGES) ? ei_src[e] : -1;
        s[k] = v;
        if (v >= 0) atomicAdd(&cnt[v >> 8], 1);
    }
    __syncthreads();
    if (t < GRP) cur[t] = atomicAdd(&gcnt[t], cnt[t]);
    __syncthreads();
    #pragma unroll
    for (int k = 0; k < 8; k++) {
        int v = s[k];
        if (v < 0) continue;
        int e = base + k * 256 + t;
        int g = v >> 8;
        int slot = atomicAdd(&cur[g], 1);
        if (slot >= GCAP) continue;
        size_t sb = (size_t)g * GCAP + slot;
        nid[sb] = (unsigned short)(v & 255);
        const float4* er = (const float4*)(ea + (size_t)e * EDGE_DIM);
        float4 a0 = er[0], a1 = er[1], a2 = er[2], a3 = er[3];
        float4 a4 = er[4], a5 = er[5], a6 = er[6], a7 = er[7];
        uint4* dst = (uint4*)(payload + sb * EDGE_DIM);
        dst[0] = pack8(a0, a1);
        dst[1] = pack8(a2, a3);
        dst[2] = pack8(a4, a5);
        dst[3] = pack8(a6, a7);
    }
}

// ---------------- K_B: per-group stream + MFMA proj + LDS accumulate ---------
// One block per group. Streams the slab coalesced (lane = 16B A-frag of one
// edge), projects 16 edges/MFMA-set, relu, ds_add_f32 into acc[node][ch]
// (pad 65 breaks bank conflicts); degree counted in LDS; divide + write ntf.
__global__ __launch_bounds__(256) void k_accum(const int* __restrict__ gcnt,
                                               const _Float16* __restrict__ payload,
                                               const unsigned short* __restrict__ nid,
                                               const float* __restrict__ Wt,
                                               const float* __restrict__ bt,
                                               float* __restrict__ ntf) {
    __shared__ float accs[256 * 65];   // 66.6KB
    __shared__ int dcnt[256];
    int t = threadIdx.x;
    int lane = t & 63, wv = t >> 6, col = lane & 15, q = lane >> 4;
    for (int i = t; i < 256 * 65; i += 256) accs[i] = 0.f;
    if (t < 256) dcnt[t] = 0;
    f16x8 bf[4];
    float bias[4];
    #pragma unroll
    for (int nt = 0; nt < 4; nt++) {
        const float4* wr = (const float4*)(Wt + (size_t)(nt * 16 + col) * EDGE_DIM + q * 8);
        bf[nt] = cvt8(wr[0], wr[1]);
        bias[nt] = bt[nt * 16 + col];
    }
    __syncthreads();
    int g = blockIdx.x;
    int sz = min(gcnt[g], GCAP);
    const _Float16* pl = payload + (size_t)g * GCAP * EDGE_DIM;
    const unsigned short* nd = nid + (size_t)g * GCAP;
    f32x4 z = {0.f, 0.f, 0.f, 0.f};
    for (int i0 = wv * 16; i0 < sz; i0 += 64) {
        int cnt_b = min(16, sz - i0);
        int ecol = col < cnt_b ? col : cnt_b - 1;
        f16x8 af = *(const f16x8*)(pl + (size_t)(i0 + ecol) * EDGE_DIM + q * 8);
        f32x4 d0 = __builtin_amdgcn_mfma_f32_16x16x32_f16(af, bf[0], z, 0, 0, 0);
        f32x4 d1 = __builtin_amdgcn_mfma_f32_16x16x32_f16(af, bf[1], z, 0, 0, 0);
        f32x4 d2 = __builtin_amdgcn_mfma_f32_16x16x32_f16(af, bf[2], z, 0, 0, 0);
        f32x4 d3 = __builtin_amdgcn_mfma_f32_16x16x32_f16(af, bf[3], z, 0, 0, 0);
        #pragma unroll
        for (int r = 0; r < 4; r++) {
            int er = q * 4 + r;
            if (er < cnt_b) {
                int node = nd[i0 + er];
                float* row = &accs[node * 65];
                atomicAdd(&row[col],      fmaxf(d0[r] + bias[0], 0.f));
                atomicAdd(&row[16 + col], fmaxf(d1[r] + bias[1], 0.f));
                atomicAdd(&row[32 + col], fmaxf(d2[r] + bias[2], 0.f));
                atomicAdd(&row[48 + col], fmaxf(d3[r] + bias[3], 0.f));
                if (col == 0) atomicAdd(&dcnt[node], 1);
            }
        }
    }
    __syncthreads();
    int gn0 = g * 256;
    for (int idx = t; idx < 256 * 64; idx += 256) {
        int nl = idx >> 6, ch = idx & 63;
        int n = gn0 + nl;
        if (n < N_NODES)
            ntf[(size_t)n * ADP + ch] = accs[nl * 65 + ch] / fmaxf((float)dcnt[nl], 1.f);
    }
}

// ---------------- K4: node_feat = relu(x @ W_down^T + b) via MFMA ------------
__global__ __launch_bounds__(256) void k_down(const float* __restrict__ x,
                                              const float* __restrict__ Wd,
                                              const float* __restrict__ bd,
                                              float* __restrict__ nfeat) {
    __shared__ f16x8 wlds[8][4][64];   // [kc][nt][lane] = 32KB
    int t = threadIdx.x;
    int lane = t & 63, col = lane & 15, q = lane >> 4;
    for (int f = t; f < 8 * 4 * 64; f += 256) {
        int l = f & 63, ntk = f >> 6;
        int nt = ntk & 3, kc = ntk >> 2;
        const float4* wr = (const float4*)(Wd + (size_t)(nt * 16 + (l & 15)) * IN_CH
                                           + kc * 32 + (l >> 4) * 8);
        wlds[kc][nt][l] = cvt8(wr[0], wr[1]);
    }
    __syncthreads();
    int tile = blockIdx.x * 4 + (t >> 6);
    if (tile >= NT16) return;
    int n0 = tile * 16;
    float bias[4];
    #pragma unroll
    for (int nt = 0; nt < 4; nt++) bias[nt] = bd[nt * 16 + col];
    f32x4 z = {0.f, 0.f, 0.f, 0.f};
    f32x4 acc[4];
    #pragma unroll
    for (int nt = 0; nt < 4; nt++) acc[nt] = z;
    #pragma unroll
    for (int kc = 0; kc < 8; kc++) {
        const float4* xr = (const float4*)(x + (size_t)(n0 + col) * IN_CH + kc * 32 + q * 8);
        float4 v0 = xr[0], v1 = xr[1];
        f16x8 af = cvt8(v0, v1);
        #pragma unroll
        for (int nt = 0; nt < 4; nt++)
            acc[nt] = __builtin_amdgcn_mfma_f32_16x16x32_f16(af, wlds[kc][nt][lane], acc[nt], 0, 0, 0);
    }
    #pragma unroll
    for (int nt = 0; nt < 4; nt++)
        #pragma unroll
        for (int r = 0; r < 4; r++)
            nfeat[(size_t)(n0 + q * 4 + r) * ADP + nt * 16 + col] = fmaxf(acc[nt][r] + bias[nt], 0.f);
}

// ---------------- K5: fused = relu([nf|ntf] @ Wf^T + b) via MFMA -------------
__global__ __launch_bounds__(256) void k_fuse(const float* __restrict__ nfeat,
                                              const float* __restrict__ ntf,
                                              const float* __restrict__ Wf,
                                              const float* __restrict__ bf_,
                                              float* __restrict__ fused) {
    __shared__ f16x8 wlds[4][4][64];   // 16KB
    int t = threadIdx.x;
    int lane = t & 63, col = lane & 15, q = lane >> 4;
    for (int f = t; f < 4 * 4 * 64; f += 256) {
        int l = f & 63, ntk = f >> 6;
        int nt = ntk & 3, kc = ntk >> 2;
        const float4* wr = (const float4*)(Wf + (size_t)(nt * 16 + (l & 15)) * (2 * ADP)
                                           + kc * 32 + (l >> 4) * 8);
        wlds[kc][nt][l] = cvt8(wr[0], wr[1]);
    }
    __syncthreads();
    int tile = blockIdx.x * 4 + (t >> 6);
    if (tile >= NT16) return;
    int n0 = tile * 16;
    float bias[4];
    #pragma unroll
    for (int nt = 0; nt < 4; nt++) bias[nt] = bf_[nt * 16 + col];
    f32x4 z = {0.f, 0.f, 0.f, 0.f};
    f32x4 acc[4];
    #pragma unroll
    for (int nt = 0; nt < 4; nt++) acc[nt] = z;
    #pragma unroll
    for (int kc = 0; kc < 4; kc++) {
        const float* srcb = (kc < 2) ? nfeat : ntf;
        int ko = (kc & 1) * 32;
        const float4* xr = (const float4*)(srcb + (size_t)(n0 + col) * ADP + ko + q * 8);
        float4 v0 = xr[0], v1 = xr[1];
        f16x8 af = cvt8(v0, v1);
        #pragma unroll
        for (int nt = 0; nt < 4; nt++)
            acc[nt] = __builtin_amdgcn_mfma_f32_16x16x32_f16(af, wlds[kc][nt][lane], acc[nt], 0, 0, 0);
    }
    #pragma unroll
    for (int nt = 0; nt < 4; nt++)
        #pragma unroll
        for (int r = 0; r < 4; r++)
            fused[(size_t)(n0 + q * 4 + r) * ADP + nt * 16 + col] = fmaxf(acc[nt][r] + bias[nt], 0.f);
}

// ---------------- K6: out = x + fused @ Wu^T + bu via MFMA -------------------
__global__ __launch_bounds__(256) void k_up(const float* __restrict__ fused,
                                            const float* __restrict__ x,
                                            const float* __restrict__ Wu,
                                            const float* __restrict__ bu,
                                            float* __restrict__ out) {
    __shared__ f16x8 wlds[2][16][64];   // 32KB
    int t = threadIdx.x;
    int lane = t & 63, col = lane & 15, q = lane >> 4;
    for (int f = t; f < 2 * 16 * 64; f += 256) {
        int l = f & 63, ntk = f >> 6;
        int nt = ntk & 15, kc = ntk >> 4;
        const float4* wr = (const float4*)(Wu + (size_t)(nt * 16 + (l & 15)) * ADP
                                           + kc * 32 + (l >> 4) * 8);
        wlds[kc][nt][l] = cvt8(wr[0], wr[1]);
    }
    __syncthreads();
    int tile = blockIdx.x * 4 + (t >> 6);
    if (tile >= NT16) return;
    int n0 = tile * 16;
    f32x4 z = {0.f, 0.f, 0.f, 0.f};
    f32x4 acc[16];
    #pragma unroll
    for (int nt = 0; nt < 16; nt++) acc[nt] = z;
    #pragma unroll
    for (int kc = 0; kc < 2; kc++) {
        const float4* xr = (const float4*)(fused + (size_t)(n0 + col) * ADP + kc * 32 + q * 8);
        float4 v0 = xr[0], v1 = xr[1];
        f16x8 af = cvt8(v0, v1);
        #pragma unroll
        for (int nt = 0; nt < 16; nt++)
            acc[nt] = __builtin_amdgcn_mfma_f32_16x16x32_f16(af, wlds[kc][nt][lane], acc[nt], 0, 0, 0);
    }
    #pragma unroll
    for (int nt = 0; nt < 16; nt++) {
        float b = bu[nt * 16 + col];
        #pragma unroll
        for (int r = 0; r < 4; r++) {
            size_t idx = (size_t)(n0 + q * 4 + r) * IN_CH + nt * 16 + col;
            out[idx] = x[idx] + acc[nt][r] + b;
        }
    }
}

extern "C" void kernel_launch(void* const* d_in, const int* in_sizes, int n_in,
                              void* d_out, int out_size, void* d_ws, size_t ws_size,
                              hipStream_t stream) {
    const float* x   = (const float*)d_in[0];
    const int*   ei  = (const int*)d_in[1];     // [2, E]; row 0 = src
    const float* ea  = (const float*)d_in[2];
    const float* Wd  = (const float*)d_in[3];
    const float* bd  = (const float*)d_in[4];
    const float* Wt  = (const float*)d_in[5];
    const float* bt  = (const float*)d_in[6];
    const float* Wf  = (const float*)d_in[7];
    const float* bf  = (const float*)d_in[8];
    const float* Wu  = (const float*)d_in[9];
    const float* bu  = (const float*)d_in[10];
    float* out = (float*)d_out;

    int* gcnt = (int*)d_ws;                                        // [256]
    unsigned short* nid = (unsigned short*)(gcnt + 256);           // [GRP*GCAP] = 4.8MB
    float* ntf   = (float*)(nid + (size_t)GRP * GCAP);             // [N*64] 12.8MB
    float* nfeat = ntf + (size_t)N_NODES * ADP;                    // 12.8MB
    float* fused = nfeat + (size_t)N_NODES * ADP;                  // 12.8MB
    _Float16* payload = (_Float16*)(fused + (size_t)N_NODES * ADP); // [GRP*GCAP*32] = 154MB

    (void)hipMemsetAsync(gcnt, 0, 256 * sizeof(int), stream);

    k_bucket<<<NB_BUCKET, 256, 0, stream>>>(ei, ea, gcnt, payload, nid);
    k_accum <<<     GRP, 256, 0, stream>>>(gcnt, payload, nid, Wt, bt, ntf);
    k_down  <<< NB_GEMM, 256, 0, stream>>>(x, Wd, bd, nfeat);
    k_fuse  <<< NB_GEMM, 256, 0, stream>>>(nfeat, ntf, Wf, bf, fused);
    k_up    <<< NB_GEMM, 256, 0, stream>>>(fused, x, Wu, bu, out);
}

// Round 5
// 555.764 us; speedup vs baseline: 2.0825x; 2.0825x over previous
//
#include <hip/hip_runtime.h>

#define N_NODES 50000
#define N_EDGES 1600000
#define IN_CH   256
#define ADP     64
#define EDGE_DIM 32
#define GRP     196     // ceil(50000/256) node groups
#define GCAP    12288   // per-group slab capacity (mean 8163, sd ~90 -> 45 sigma)
#define EPB_A   2048    // edges per block in k_bucket
#define NB_BUCKET ((N_EDGES + EPB_A - 1) / EPB_A)   // 782
#define NT16    (N_NODES / 16)                      // 3125 node tiles
#define NB_GEMM ((NT16 + 3) / 4)                    // 782
#define NB_GATHER (GRP * 64)                        // 12544 blocks, 4 nodes each

typedef __fp16 h2 __attribute__((ext_vector_type(2)));
typedef _Float16 f16x8 __attribute__((ext_vector_type(8)));
typedef float f32x4 __attribute__((ext_vector_type(4)));
union UH { unsigned int u; h2 h; };

__device__ inline f16x8 cvt8(float4 a, float4 b) {
    union { f16x8 v; h2 h[4]; } r;
    r.h[0] = __builtin_amdgcn_cvt_pkrtz(a.x, a.y);
    r.h[1] = __builtin_amdgcn_cvt_pkrtz(a.z, a.w);
    r.h[2] = __builtin_amdgcn_cvt_pkrtz(b.x, b.y);
    r.h[3] = __builtin_amdgcn_cvt_pkrtz(b.z, b.w);
    return r.v;
}

__device__ inline uint4 pack8(float4 a, float4 b) {
    UH p0, p1, p2, p3;
    p0.h = __builtin_amdgcn_cvt_pkrtz(a.x, a.y);
    p1.h = __builtin_amdgcn_cvt_pkrtz(a.z, a.w);
    p2.h = __builtin_amdgcn_cvt_pkrtz(b.x, b.y);
    p3.h = __builtin_amdgcn_cvt_pkrtz(b.z, b.w);
    return make_uint4(p0.u, p1.u, p2.u, p3.u);
}

// ---------------- K_A: bucket by 256-node group, carrying f16 payload --------
// (proven correct in R4) Streams ea coalesced; writes each edge's 64B f16 row
// + node-in-group id into the group slab at a block-reserved frontier window.
__global__ __launch_bounds__(256) void k_bucket(const int* __restrict__ ei_src,
                                                const float* __restrict__ ea,
                                                int* __restrict__ gcnt,
                                                _Float16* __restrict__ payload,
                                                unsigned short* __restrict__ nid) {
    __shared__ int cnt[GRP];
    __shared__ int cur[GRP];
    int t = threadIdx.x;
    if (t < GRP) cnt[t] = 0;
    __syncthreads();
    int base = blockIdx.x * EPB_A;
    int s[8];
    #pragma unroll
    for (int k = 0; k < 8; k++) {
        int e = base + k * 256 + t;
        int v = (e < N_EDGES) ? ei_src[e] : -1;
        s[k] = v;
        if (v >= 0) atomicAdd(&cnt[v >> 8], 1);
    }
    __syncthreads();
    if (t < GRP) cur[t] = atomicAdd(&gcnt[t], cnt[t]);
    __syncthreads();
    #pragma unroll
    for (int k = 0; k < 8; k++) {
        int v = s[k];
        if (v < 0) continue;
        int e = base + k * 256 + t;
        int g = v >> 8;
        int slot = atomicAdd(&cur[g], 1);
        if (slot >= GCAP) continue;
        size_t sb = (size_t)g * GCAP + slot;
        nid[sb] = (unsigned short)(v & 255);
        const float4* er = (const float4*)(ea + (size_t)e * EDGE_DIM);
        float4 a0 = er[0], a1 = er[1], a2 = er[2], a3 = er[3];
        float4 a4 = er[4], a5 = er[5], a6 = er[6], a7 = er[7];
        uint4* dst = (uint4*)(payload + sb * EDGE_DIM);
        dst[0] = pack8(a0, a1);
        dst[1] = pack8(a2, a3);
        dst[2] = pack8(a4, a5);
        dst[3] = pack8(a6, a7);
    }
}

// ---------------- K_B: per-group deg + slab-local node index lists -----------
// One block per group. Count 256 node degrees, LDS scan (slab-local offsets),
// scatter slab indices (ushort) into per-node contiguous lists. No global scan.
__global__ __launch_bounds__(512) void k_build(const int* __restrict__ gcnt,
                                               const unsigned short* __restrict__ nid,
                                               int* __restrict__ deg,
                                               int* __restrict__ loffs,
                                               unsigned short* __restrict__ lidx) {
    __shared__ int a[256], b[256], dcnt[256], cur[256];
    int t = threadIdx.x;
    int g = blockIdx.x;
    int sz = min(gcnt[g], GCAP);
    const unsigned short* nd = nid + (size_t)g * GCAP;
    unsigned short* li = lidx + (size_t)g * GCAP;
    if (t < 256) dcnt[t] = 0;
    __syncthreads();
    for (int i = t; i < sz; i += 512) atomicAdd(&dcnt[nd[i]], 1);
    __syncthreads();
    if (t < 256) a[t] = dcnt[t];
    __syncthreads();
    int* sp = a; int* dp = b;
    for (int o = 1; o < 256; o <<= 1) {
        if (t < 256) { int v2 = sp[t]; if (t >= o) v2 += sp[t - o]; dp[t] = v2; }
        __syncthreads();
        int* tmp = sp; sp = dp; dp = tmp;
    }
    if (t < 256) {
        int v = dcnt[t];
        int pref = sp[t] - v;
        int n = g * 256 + t;
        if (n < N_NODES) { deg[n] = v; loffs[n] = pref; }
        cur[t] = pref;
    }
    __syncthreads();
    for (int i = t; i < sz; i += 512) {
        int slot = atomicAdd(&cur[nd[i]], 1);
        li[slot] = (unsigned short)i;
    }
}

// ---------------- K3: gather (L2-local slab) + MFMA proj + mean --------------
// R3-proven structure: one wave per node, register accumulation, no atomics.
// Reads 64B f16 payload rows random-within-786KB-slab (L2-resident with the
// XCD swizzle: a group's 64 blocks land on one XCD).
__global__ __launch_bounds__(256) void k_gather(const float* __restrict__ Wt,
                                                const float* __restrict__ bt,
                                                const int* __restrict__ deg,
                                                const int* __restrict__ loffs,
                                                const unsigned short* __restrict__ lidx,
                                                const _Float16* __restrict__ payload,
                                                float* __restrict__ ntf) {
    int t = threadIdx.x;
    int lane = t & 63;
    int col = lane & 15, q = lane >> 4;
    f16x8 bf[4];
    float bias[4];
    #pragma unroll
    for (int nt = 0; nt < 4; nt++) {
        const float4* wr = (const float4*)(Wt + (size_t)(nt * 16 + col) * EDGE_DIM + q * 8);
        bf[nt] = cvt8(wr[0], wr[1]);
        bias[nt] = bt[nt * 16 + col];
    }
    // XCD swizzle: blocks with equal (orig & 7) are presumed same-XCD ->
    // give them consecutive logical ids so each group's slab stays in one L2.
    int orig = blockIdx.x;
    int logical = (orig & 7) * (NB_GATHER / 8) + (orig >> 3);
    int n = logical * 4 + (t >> 6);
    if (n >= N_NODES) return;
    int g = n >> 8;
    int st = loffs[n], d = deg[n];
    const unsigned short* li = lidx + (size_t)g * GCAP;
    const _Float16* pl = payload + (size_t)g * GCAP * EDGE_DIM;
    float s0 = 0.f, s1 = 0.f, s2 = 0.f, s3 = 0.f;
    f32x4 z = {0.f, 0.f, 0.f, 0.f};
    int base = 0;
    for (; base + 32 <= d; base += 32) {
        int i0 = li[st + base + col];
        int i1 = li[st + base + 16 + col];
        f16x8 afA = *(const f16x8*)(pl + (size_t)i0 * EDGE_DIM + q * 8);
        f16x8 afB = *(const f16x8*)(pl + (size_t)i1 * EDGE_DIM + q * 8);
        f32x4 dA0 = __builtin_amdgcn_mfma_f32_16x16x32_f16(afA, bf[0], z, 0, 0, 0);
        f32x4 dA1 = __builtin_amdgcn_mfma_f32_16x16x32_f16(afA, bf[1], z, 0, 0, 0);
        f32x4 dA2 = __builtin_amdgcn_mfma_f32_16x16x32_f16(afA, bf[2], z, 0, 0, 0);
        f32x4 dA3 = __builtin_amdgcn_mfma_f32_16x16x32_f16(afA, bf[3], z, 0, 0, 0);
        f32x4 dB0 = __builtin_amdgcn_mfma_f32_16x16x32_f16(afB, bf[0], z, 0, 0, 0);
        f32x4 dB1 = __builtin_amdgcn_mfma_f32_16x16x32_f16(afB, bf[1], z, 0, 0, 0);
        f32x4 dB2 = __builtin_amdgcn_mfma_f32_16x16x32_f16(afB, bf[2], z, 0, 0, 0);
        f32x4 dB3 = __builtin_amdgcn_mfma_f32_16x16x32_f16(afB, bf[3], z, 0, 0, 0);
        #pragma unroll
        for (int r = 0; r < 4; r++) {
            s0 += fmaxf(dA0[r] + bias[0], 0.f) + fmaxf(dB0[r] + bias[0], 0.f);
            s1 += fmaxf(dA1[r] + bias[1], 0.f) + fmaxf(dB1[r] + bias[1], 0.f);
            s2 += fmaxf(dA2[r] + bias[2], 0.f) + fmaxf(dB2[r] + bias[2], 0.f);
            s3 += fmaxf(dA3[r] + bias[3], 0.f) + fmaxf(dB3[r] + bias[3], 0.f);
        }
    }
    for (; base < d; base += 16) {
        int cnt = d - base; if (cnt > 16) cnt = 16;
        int i0 = li[st + base + (col < cnt ? col : cnt - 1)];
        f16x8 af = *(const f16x8*)(pl + (size_t)i0 * EDGE_DIM + q * 8);
        f32x4 d0 = __builtin_amdgcn_mfma_f32_16x16x32_f16(af, bf[0], z, 0, 0, 0);
        f32x4 d1 = __builtin_amdgcn_mfma_f32_16x16x32_f16(af, bf[1], z, 0, 0, 0);
        f32x4 d2 = __builtin_amdgcn_mfma_f32_16x16x32_f16(af, bf[2], z, 0, 0, 0);
        f32x4 d3 = __builtin_amdgcn_mfma_f32_16x16x32_f16(af, bf[3], z, 0, 0, 0);
        #pragma unroll
        for (int r = 0; r < 4; r++) {
            bool ok = (q * 4 + r) < cnt;
            s0 += ok ? fmaxf(d0[r] + bias[0], 0.f) : 0.f;
            s1 += ok ? fmaxf(d1[r] + bias[1], 0.f) : 0.f;
            s2 += ok ? fmaxf(d2[r] + bias[2], 0.f) : 0.f;
            s3 += ok ? fmaxf(d3[r] + bias[3], 0.f) : 0.f;
        }
    }
    s0 += __shfl_xor(s0, 16, 64); s0 += __shfl_xor(s0, 32, 64);
    s1 += __shfl_xor(s1, 16, 64); s1 += __shfl_xor(s1, 32, 64);
    s2 += __shfl_xor(s2, 16, 64); s2 += __shfl_xor(s2, 32, 64);
    s3 += __shfl_xor(s3, 16, 64); s3 += __shfl_xor(s3, 32, 64);
    float res = (q == 0) ? s0 : (q == 1) ? s1 : (q == 2) ? s2 : s3;
    ntf[(size_t)n * ADP + lane] = res / fmaxf((float)d, 1.f);
}

// ---------------- K4: node_feat = relu(x @ W_down^T + b) via MFMA ------------
__global__ __launch_bounds__(256) void k_down(const float* __restrict__ x,
                                              const float* __restrict__ Wd,
                                              const float* __restrict__ bd,
                                              float* __restrict__ nfeat) {
    __shared__ f16x8 wlds[8][4][64];   // [kc][nt][lane] = 32KB
    int t = threadIdx.x;
    int lane = t & 63, col = lane & 15, q = lane >> 4;
    for (int f = t; f < 8 * 4 * 64; f += 256) {
        int l = f & 63, ntk = f >> 6;
        int nt = ntk & 3, kc = ntk >> 2;
        const float4* wr = (const float4*)(Wd + (size_t)(nt * 16 + (l & 15)) * IN_CH
                                           + kc * 32 + (l >> 4) * 8);
        wlds[kc][nt][l] = cvt8(wr[0], wr[1]);
    }
    __syncthreads();
    int tile = blockIdx.x * 4 + (t >> 6);
    if (tile >= NT16) return;
    int n0 = tile * 16;
    float bias[4];
    #pragma unroll
    for (int nt = 0; nt < 4; nt++) bias[nt] = bd[nt * 16 + col];
    f32x4 z = {0.f, 0.f, 0.f, 0.f};
    f32x4 acc[4];
    #pragma unroll
    for (int nt = 0; nt < 4; nt++) acc[nt] = z;
    #pragma unroll
    for (int kc = 0; kc < 8; kc++) {
        const float4* xr = (const float4*)(x + (size_t)(n0 + col) * IN_CH + kc * 32 + q * 8);
        float4 v0 = xr[0], v1 = xr[1];
        f16x8 af = cvt8(v0, v1);
        #pragma unroll
        for (int nt = 0; nt < 4; nt++)
            acc[nt] = __builtin_amdgcn_mfma_f32_16x16x32_f16(af, wlds[kc][nt][lane], acc[nt], 0, 0, 0);
    }
    #pragma unroll
    for (int nt = 0; nt < 4; nt++)
        #pragma unroll
        for (int r = 0; r < 4; r++)
            nfeat[(size_t)(n0 + q * 4 + r) * ADP + nt * 16 + col] = fmaxf(acc[nt][r] + bias[nt], 0.f);
}

// ---------------- K5: fused = relu([nf|ntf] @ Wf^T + b) via MFMA -------------
__global__ __launch_bounds__(256) void k_fuse(const float* __restrict__ nfeat,
                                              const float* __restrict__ ntf,
                                              const float* __restrict__ Wf,
                                              const float* __restrict__ bf_,
                                              float* __restrict__ fused) {
    __shared__ f16x8 wlds[4][4][64];   // 16KB
    int t = threadIdx.x;
    int lane = t & 63, col = lane & 15, q = lane >> 4;
    for (int f = t; f < 4 * 4 * 64; f += 256) {
        int l = f & 63, ntk = f >> 6;
        int nt = ntk & 3, kc = ntk >> 2;
        const float4* wr = (const float4*)(Wf + (size_t)(nt * 16 + (l & 15)) * (2 * ADP)
                                           + kc * 32 + (l >> 4) * 8);
        wlds[kc][nt][l] = cvt8(wr[0], wr[1]);
    }
    __syncthreads();
    int tile = blockIdx.x * 4 + (t >> 6);
    if (tile >= NT16) return;
    int n0 = tile * 16;
    float bias[4];
    #pragma unroll
    for (int nt = 0; nt < 4; nt++) bias[nt] = bf_[nt * 16 + col];
    f32x4 z = {0.f, 0.f, 0.f, 0.f};
    f32x4 acc[4];
    #pragma unroll
    for (int nt = 0; nt < 4; nt++) acc[nt] = z;
    #pragma unroll
    for (int kc = 0; kc < 4; kc++) {
        const float* srcb = (kc < 2) ? nfeat : ntf;
        int ko = (kc & 1) * 32;
        const float4* xr = (const float4*)(srcb + (size_t)(n0 + col) * ADP + ko + q * 8);
        float4 v0 = xr[0], v1 = xr[1];
        f16x8 af = cvt8(v0, v1);
        #pragma unroll
        for (int nt = 0; nt < 4; nt++)
            acc[nt] = __builtin_amdgcn_mfma_f32_16x16x32_f16(af, wlds[kc][nt][lane], acc[nt], 0, 0, 0);
    }
    #pragma unroll
    for (int nt = 0; nt < 4; nt++)
        #pragma unroll
        for (int r = 0; r < 4; r++)
            fused[(size_t)(n0 + q * 4 + r) * ADP + nt * 16 + col] = fmaxf(acc[nt][r] + bias[nt], 0.f);
}

// ---------------- K6: out = x + fused @ Wu^T + bu via MFMA -------------------
__global__ __launch_bounds__(256) void k_up(const float* __restrict__ fused,
                                            const float* __restrict__ x,
                                            const float* __restrict__ Wu,
                                            const float* __restrict__ bu,
                                            float* __restrict__ out) {
    __shared__ f16x8 wlds[2][16][64];   // 32KB
    int t = threadIdx.x;
    int lane = t & 63, col = lane & 15, q = lane >> 4;
    for (int f = t; f < 2 * 16 * 64; f += 256) {
        int l = f & 63, ntk = f >> 6;
        int nt = ntk & 15, kc = ntk >> 4;
        const float4* wr = (const float4*)(Wu + (size_t)(nt * 16 + (l & 15)) * ADP
                                           + kc * 32 + (l >> 4) * 8);
        wlds[kc][nt][l] = cvt8(wr[0], wr[1]);
    }
    __syncthreads();
    int tile = blockIdx.x * 4 + (t >> 6);
    if (tile >= NT16) return;
    int n0 = tile * 16;
    f32x4 z = {0.f, 0.f, 0.f, 0.f};
    f32x4 acc[16];
    #pragma unroll
    for (int nt = 0; nt < 16; nt++) acc[nt] = z;
    #pragma unroll
    for (int kc = 0; kc < 2; kc++) {
        const float4* xr = (const float4*)(fused + (size_t)(n0 + col) * ADP + kc * 32 + q * 8);
        float4 v0 = xr[0], v1 = xr[1];
        f16x8 af = cvt8(v0, v1);
        #pragma unroll
        for (int nt = 0; nt < 16; nt++)
            acc[nt] = __builtin_amdgcn_mfma_f32_16x16x32_f16(af, wlds[kc][nt][lane], acc[nt], 0, 0, 0);
    }
    #pragma unroll
    for (int nt = 0; nt < 16; nt++) {
        float b = bu[nt * 16 + col];
        #pragma unroll
        for (int r = 0; r < 4; r++) {
            size_t idx = (size_t)(n0 + q * 4 + r) * IN_CH + nt * 16 + col;
            out[idx] = x[idx] + acc[nt][r] + b;
        }
    }
}

extern "C" void kernel_launch(void* const* d_in, const int* in_sizes, int n_in,
                              void* d_out, int out_size, void* d_ws, size_t ws_size,
                              hipStream_t stream) {
    const float* x   = (const float*)d_in[0];
    const int*   ei  = (const int*)d_in[1];     // [2, E]; row 0 = src
    const float* ea  = (const float*)d_in[2];
    const float* Wd  = (const float*)d_in[3];
    const float* bd  = (const float*)d_in[4];
    const float* Wt  = (const float*)d_in[5];
    const float* bt  = (const float*)d_in[6];
    const float* Wf  = (const float*)d_in[7];
    const float* bf  = (const float*)d_in[8];
    const float* Wu  = (const float*)d_in[9];
    const float* bu  = (const float*)d_in[10];
    float* out = (float*)d_out;

    int* gcnt  = (int*)d_ws;                                        // [256]
    int* deg   = gcnt + 256;                                        // [N]
    int* loffs = deg + N_NODES;                                     // [N]
    unsigned short* nid  = (unsigned short*)(loffs + N_NODES);      // [GRP*GCAP] 4.8MB
    unsigned short* lidx = nid + (size_t)GRP * GCAP;                // [GRP*GCAP] 4.8MB
    float* ntf   = (float*)(lidx + (size_t)GRP * GCAP);             // [N*64] 12.8MB
    float* nfeat = ntf + (size_t)N_NODES * ADP;                     // 12.8MB
    float* fused = nfeat + (size_t)N_NODES * ADP;                   // 12.8MB
    _Float16* payload = (_Float16*)(fused + (size_t)N_NODES * ADP); // [GRP*GCAP*32] 154MB

    (void)hipMemsetAsync(gcnt, 0, 256 * sizeof(int), stream);

    k_bucket<<<NB_BUCKET, 256, 0, stream>>>(ei, ea, gcnt, payload, nid);
    k_build <<<     GRP, 512, 0, stream>>>(gcnt, nid, deg, loffs, lidx);
    k_gather<<<NB_GATHER, 256, 0, stream>>>(Wt, bt, deg, loffs, lidx, payload, ntf);
    k_down  <<< NB_GEMM, 256, 0, stream>>>(x, Wd, bd, nfeat);
    k_fuse  <<< NB_GEMM, 256, 0, stream>>>(nfeat, ntf, Wf, bf, fused);
    k_up    <<< NB_GEMM, 256, 0, stream>>>(fused, x, Wu, bu, out);
}

// Round 6
// 461.375 us; speedup vs baseline: 2.5086x; 1.2046x over previous
//
#include <hip/hip_runtime.h>

#define N_NODES 50000
#define N_EDGES 1600000
#define IN_CH   256
#define ADP     64
#define EDGE_DIM 32
#define GRP     196     // ceil(50000/256) node groups
#define GCAP    12288   // per-group bucket capacity (mean 8163, sd ~90)
#define EPB_A   2048    // edges per block in k_bucket
#define NB_BUCKET ((N_EDGES + EPB_A - 1) / EPB_A)   // 782
#define NT16    (N_NODES / 16)                      // 3125 node tiles
#define NB_GEMM ((NT16 + 3) / 4)                    // 782

typedef __fp16 h2 __attribute__((ext_vector_type(2)));
typedef _Float16 f16x8 __attribute__((ext_vector_type(8)));
typedef float f32x4 __attribute__((ext_vector_type(4)));

__device__ inline f16x8 cvt8(float4 a, float4 b) {
    union { f16x8 v; h2 h[4]; } r;
    r.h[0] = __builtin_amdgcn_cvt_pkrtz(a.x, a.y);
    r.h[1] = __builtin_amdgcn_cvt_pkrtz(a.z, a.w);
    r.h[2] = __builtin_amdgcn_cvt_pkrtz(b.x, b.y);
    r.h[3] = __builtin_amdgcn_cvt_pkrtz(b.z, b.w);
    return r.v;
}

// ---------------- K_A: coarse bucket by 256-node group (R3-proven) -----------
__global__ __launch_bounds__(256) void k_bucket(const int* __restrict__ ei_src,
                                                int* __restrict__ gcnt,
                                                int* __restrict__ gbuf) {
    __shared__ int cnt[GRP];
    __shared__ int cur[GRP];
    int t = threadIdx.x;
    if (t < GRP) cnt[t] = 0;
    __syncthreads();
    int base = blockIdx.x * EPB_A;
    int s[8];
    #pragma unroll
    for (int k = 0; k < 8; k++) {
        int e = base + k * 256 + t;
        int v = (e < N_EDGES) ? ei_src[e] : -1;
        s[k] = v;
        if (v >= 0) atomicAdd(&cnt[v >> 8], 1);
    }
    __syncthreads();
    if (t < GRP) cur[t] = atomicAdd(&gcnt[t], cnt[t]);
    __syncthreads();
    #pragma unroll
    for (int k = 0; k < 8; k++) {
        int v = s[k];
        if (v >= 0) {
            int e = base + k * 256 + t;
            int g = v >> 8;
            int slot = atomicAdd(&cur[g], 1);
            if (slot < GCAP)
                gbuf[g * GCAP + slot] = (e << 8) | (v & 255);
        }
    }
}

// ---------------- K_B: per-group deg/offs/elist build (R3-proven) ------------
__global__ __launch_bounds__(512) void k_build(const int* __restrict__ gcnt,
                                               const int* __restrict__ gbuf,
                                               int* __restrict__ deg,
                                               int* __restrict__ offs,
                                               int* __restrict__ elist) {
    __shared__ int a[256], b[256], dcnt[256], cur[256];
    int t = threadIdx.x;
    int g = blockIdx.x;
    // every block scans the 196 capped group counts -> its global base
    if (t < 256) a[t] = (t < GRP) ? min(gcnt[t], GCAP) : 0;
    __syncthreads();
    int* sp = a; int* dp = b;
    for (int o = 1; o < 256; o <<= 1) {
        if (t < 256) { int v2 = sp[t]; if (t >= o) v2 += sp[t - o]; dp[t] = v2; }
        __syncthreads();
        int* tmp = sp; sp = dp; dp = tmp;
    }
    int base = (g == 0) ? 0 : sp[g - 1];
    int sz = min(gcnt[g], GCAP);
    if (t < 256) dcnt[t] = 0;
    __syncthreads();
    const int* src = gbuf + (size_t)g * GCAP;
    for (int i = t; i < sz; i += 512) atomicAdd(&dcnt[src[i] & 255], 1);
    __syncthreads();
    if (t < 256) a[t] = dcnt[t];
    __syncthreads();
    sp = a; dp = b;
    for (int o = 1; o < 256; o <<= 1) {
        if (t < 256) { int v2 = sp[t]; if (t >= o) v2 += sp[t - o]; dp[t] = v2; }
        __syncthreads();
        int* tmp = sp; sp = dp; dp = tmp;
    }
    if (t < 256) {
        int v = dcnt[t];
        int pref = sp[t] - v;
        int n = g * 256 + t;
        if (n < N_NODES) { deg[n] = v; offs[n] = base + pref; }
        cur[t] = pref;
    }
    __syncthreads();
    for (int i = t; i < sz; i += 512) {
        int p = src[i];
        int slot = atomicAdd(&cur[p & 255], 1);
        elist[base + slot] = p >> 8;
    }
}

// ---------------- K3: gather + MFMA proj + mean, 4-chunk ILP -----------------
// One wave per node. Straight-line 64-edge pass: 4 independent index loads,
// then 8 independent float4 payload loads in flight (3x R3's concurrency),
// then 16 masked MFMAs. Rare (P~4e-4) d>64 tail loop.
__global__ __launch_bounds__(256) void k_gatherproj(const float* __restrict__ ea,
                                                    const int* __restrict__ offs,
                                                    const int* __restrict__ deg,
                                                    const int* __restrict__ elist,
                                                    const float* __restrict__ Wt,
                                                    const float* __restrict__ bt,
                                                    float* __restrict__ ntf) {
    int t = threadIdx.x;
    int lane = t & 63;
    int col = lane & 15, q = lane >> 4;
    int n = blockIdx.x * 4 + (t >> 6);
    if (n >= N_NODES) return;
    int st = offs[n], d = deg[n];
    f16x8 bf[4];
    float bias[4];
    #pragma unroll
    for (int nt = 0; nt < 4; nt++) {
        const float4* wr = (const float4*)(Wt + (size_t)(nt * 16 + col) * EDGE_DIM + q * 8);
        bf[nt] = cvt8(wr[0], wr[1]);
        bias[nt] = bt[nt * 16 + col];
    }
    if (d == 0) { ntf[(size_t)n * ADP + lane] = 0.f; return; }
    const float4* ea4 = (const float4*)ea;
    // 4 independent chunk-index loads (clamped duplicates hit L1)
    int idx[4];
    #pragma unroll
    for (int c = 0; c < 4; c++) {
        int p = 16 * c + col;
        idx[c] = elist[st + (p < d ? p : d - 1)];
    }
    // 8 independent payload loads
    f16x8 af[4];
    #pragma unroll
    for (int c = 0; c < 4; c++) {
        const float4* p = ea4 + (size_t)idx[c] * 8 + q * 2;
        float4 v0 = p[0], v1 = p[1];
        af[c] = cvt8(v0, v1);
    }
    float s0 = 0.f, s1 = 0.f, s2 = 0.f, s3 = 0.f;
    f32x4 z = {0.f, 0.f, 0.f, 0.f};
    #pragma unroll
    for (int c = 0; c < 4; c++) {
        f32x4 d0 = __builtin_amdgcn_mfma_f32_16x16x32_f16(af[c], bf[0], z, 0, 0, 0);
        f32x4 d1 = __builtin_amdgcn_mfma_f32_16x16x32_f16(af[c], bf[1], z, 0, 0, 0);
        f32x4 d2 = __builtin_amdgcn_mfma_f32_16x16x32_f16(af[c], bf[2], z, 0, 0, 0);
        f32x4 d3 = __builtin_amdgcn_mfma_f32_16x16x32_f16(af[c], bf[3], z, 0, 0, 0);
        #pragma unroll
        for (int r = 0; r < 4; r++) {
            bool ok = (16 * c + q * 4 + r) < d;
            s0 += ok ? fmaxf(d0[r] + bias[0], 0.f) : 0.f;
            s1 += ok ? fmaxf(d1[r] + bias[1], 0.f) : 0.f;
            s2 += ok ? fmaxf(d2[r] + bias[2], 0.f) : 0.f;
            s3 += ok ? fmaxf(d3[r] + bias[3], 0.f) : 0.f;
        }
    }
    // rare tail: d > 64
    for (int base = 64; base < d; base += 16) {
        int cnt = d - base; if (cnt > 16) cnt = 16;
        int e = elist[st + base + (col < cnt ? col : cnt - 1)];
        const float4* p = ea4 + (size_t)e * 8 + q * 2;
        float4 v0 = p[0], v1 = p[1];
        f16x8 af2 = cvt8(v0, v1);
        f32x4 d0 = __builtin_amdgcn_mfma_f32_16x16x32_f16(af2, bf[0], z, 0, 0, 0);
        f32x4 d1 = __builtin_amdgcn_mfma_f32_16x16x32_f16(af2, bf[1], z, 0, 0, 0);
        f32x4 d2 = __builtin_amdgcn_mfma_f32_16x16x32_f16(af2, bf[2], z, 0, 0, 0);
        f32x4 d3 = __builtin_amdgcn_mfma_f32_16x16x32_f16(af2, bf[3], z, 0, 0, 0);
        #pragma unroll
        for (int r = 0; r < 4; r++) {
            bool ok = (q * 4 + r) < cnt;
            s0 += ok ? fmaxf(d0[r] + bias[0], 0.f) : 0.f;
            s1 += ok ? fmaxf(d1[r] + bias[1], 0.f) : 0.f;
            s2 += ok ? fmaxf(d2[r] + bias[2], 0.f) : 0.f;
            s3 += ok ? fmaxf(d3[r] + bias[3], 0.f) : 0.f;
        }
    }
    s0 += __shfl_xor(s0, 16, 64); s0 += __shfl_xor(s0, 32, 64);
    s1 += __shfl_xor(s1, 16, 64); s1 += __shfl_xor(s1, 32, 64);
    s2 += __shfl_xor(s2, 16, 64); s2 += __shfl_xor(s2, 32, 64);
    s3 += __shfl_xor(s3, 16, 64); s3 += __shfl_xor(s3, 32, 64);
    float res = (q == 0) ? s0 : (q == 1) ? s1 : (q == 2) ? s2 : s3;
    ntf[(size_t)n * ADP + lane] = res / (float)d;
}

// ---------------- K4: node_feat = relu(x @ W_down^T + b) via MFMA ------------
__global__ __launch_bounds__(256) void k_down(const float* __restrict__ x,
                                              const float* __restrict__ Wd,
                                              const float* __restrict__ bd,
                                              float* __restrict__ nfeat) {
    __shared__ f16x8 wlds[8][4][64];   // [kc][nt][lane] = 32KB
    int t = threadIdx.x;
    int lane = t & 63, col = lane & 15, q = lane >> 4;
    for (int f = t; f < 8 * 4 * 64; f += 256) {
        int l = f & 63, ntk = f >> 6;
        int nt = ntk & 3, kc = ntk >> 2;
        const float4* wr = (const float4*)(Wd + (size_t)(nt * 16 + (l & 15)) * IN_CH
                                           + kc * 32 + (l >> 4) * 8);
        wlds[kc][nt][l] = cvt8(wr[0], wr[1]);
    }
    __syncthreads();
    int tile = blockIdx.x * 4 + (t >> 6);
    if (tile >= NT16) return;
    int n0 = tile * 16;
    float bias[4];
    #pragma unroll
    for (int nt = 0; nt < 4; nt++) bias[nt] = bd[nt * 16 + col];
    f32x4 z = {0.f, 0.f, 0.f, 0.f};
    f32x4 acc[4];
    #pragma unroll
    for (int nt = 0; nt < 4; nt++) acc[nt] = z;
    #pragma unroll
    for (int kc = 0; kc < 8; kc++) {
        const float4* xr = (const float4*)(x + (size_t)(n0 + col) * IN_CH + kc * 32 + q * 8);
        float4 v0 = xr[0], v1 = xr[1];
        f16x8 af = cvt8(v0, v1);
        #pragma unroll
        for (int nt = 0; nt < 4; nt++)
            acc[nt] = __builtin_amdgcn_mfma_f32_16x16x32_f16(af, wlds[kc][nt][lane], acc[nt], 0, 0, 0);
    }
    #pragma unroll
    for (int nt = 0; nt < 4; nt++)
        #pragma unroll
        for (int r = 0; r < 4; r++)
            nfeat[(size_t)(n0 + q * 4 + r) * ADP + nt * 16 + col] = fmaxf(acc[nt][r] + bias[nt], 0.f);
}

// ---------------- K5: fused = relu([nf|ntf] @ Wf^T + b) via MFMA -------------
__global__ __launch_bounds__(256) void k_fuse(const float* __restrict__ nfeat,
                                              const float* __restrict__ ntf,
                                              const float* __restrict__ Wf,
                                              const float* __restrict__ bf_,
                                              float* __restrict__ fused) {
    __shared__ f16x8 wlds[4][4][64];   // 16KB
    int t = threadIdx.x;
    int lane = t & 63, col = lane & 15, q = lane >> 4;
    for (int f = t; f < 4 * 4 * 64; f += 256) {
        int l = f & 63, ntk = f >> 6;
        int nt = ntk & 3, kc = ntk >> 2;
        const float4* wr = (const float4*)(Wf + (size_t)(nt * 16 + (l & 15)) * (2 * ADP)
                                           + kc * 32 + (l >> 4) * 8);
        wlds[kc][nt][l] = cvt8(wr[0], wr[1]);
    }
    __syncthreads();
    int tile = blockIdx.x * 4 + (t >> 6);
    if (tile >= NT16) return;
    int n0 = tile * 16;
    float bias[4];
    #pragma unroll
    for (int nt = 0; nt < 4; nt++) bias[nt] = bf_[nt * 16 + col];
    f32x4 z = {0.f, 0.f, 0.f, 0.f};
    f32x4 acc[4];
    #pragma unroll
    for (int nt = 0; nt < 4; nt++) acc[nt] = z;
    #pragma unroll
    for (int kc = 0; kc < 4; kc++) {
        const float* srcb = (kc < 2) ? nfeat : ntf;
        int ko = (kc & 1) * 32;
        const float4* xr = (const float4*)(srcb + (size_t)(n0 + col) * ADP + ko + q * 8);
        float4 v0 = xr[0], v1 = xr[1];
        f16x8 af = cvt8(v0, v1);
        #pragma unroll
        for (int nt = 0; nt < 4; nt++)
            acc[nt] = __builtin_amdgcn_mfma_f32_16x16x32_f16(af, wlds[kc][nt][lane], acc[nt], 0, 0, 0);
    }
    #pragma unroll
    for (int nt = 0; nt < 4; nt++)
        #pragma unroll
        for (int r = 0; r < 4; r++)
            fused[(size_t)(n0 + q * 4 + r) * ADP + nt * 16 + col] = fmaxf(acc[nt][r] + bias[nt], 0.f);
}

// ---------------- K6: out = x + fused @ Wu^T + bu via MFMA -------------------
__global__ __launch_bounds__(256) void k_up(const float* __restrict__ fused,
                                            const float* __restrict__ x,
                                            const float* __restrict__ Wu,
                                            const float* __restrict__ bu,
                                            float* __restrict__ out) {
    __shared__ f16x8 wlds[2][16][64];   // 32KB
    int t = threadIdx.x;
    int lane = t & 63, col = lane & 15, q = lane >> 4;
    for (int f = t; f < 2 * 16 * 64; f += 256) {
        int l = f & 63, ntk = f >> 6;
        int nt = ntk & 15, kc = ntk >> 4;
        const float4* wr = (const float4*)(Wu + (size_t)(nt * 16 + (l & 15)) * ADP
                                           + kc * 32 + (l >> 4) * 8);
        wlds[kc][nt][l] = cvt8(wr[0], wr[1]);
    }
    __syncthreads();
    int tile = blockIdx.x * 4 + (t >> 6);
    if (tile >= NT16) return;
    int n0 = tile * 16;
    f32x4 z = {0.f, 0.f, 0.f, 0.f};
    f32x4 acc[16];
    #pragma unroll
    for (int nt = 0; nt < 16; nt++) acc[nt] = z;
    #pragma unroll
    for (int kc = 0; kc < 2; kc++) {
        const float4* xr = (const float4*)(fused + (size_t)(n0 + col) * ADP + kc * 32 + q * 8);
        float4 v0 = xr[0], v1 = xr[1];
        f16x8 af = cvt8(v0, v1);
        #pragma unroll
        for (int nt = 0; nt < 16; nt++)
            acc[nt] = __builtin_amdgcn_mfma_f32_16x16x32_f16(af, wlds[kc][nt][lane], acc[nt], 0, 0, 0);
    }
    #pragma unroll
    for (int nt = 0; nt < 16; nt++) {
        float b = bu[nt * 16 + col];
        #pragma unroll
        for (int r = 0; r < 4; r++) {
            size_t idx = (size_t)(n0 + q * 4 + r) * IN_CH + nt * 16 + col;
            out[idx] = x[idx] + acc[nt][r] + b;
        }
    }
}

extern "C" void kernel_launch(void* const* d_in, const int* in_sizes, int n_in,
                              void* d_out, int out_size, void* d_ws, size_t ws_size,
                              hipStream_t stream) {
    const float* x   = (const float*)d_in[0];
    const int*   ei  = (const int*)d_in[1];     // [2, E]; row 0 = src
    const float* ea  = (const float*)d_in[2];
    const float* Wd  = (const float*)d_in[3];
    const float* bd  = (const float*)d_in[4];
    const float* Wt  = (const float*)d_in[5];
    const float* bt  = (const float*)d_in[6];
    const float* Wf  = (const float*)d_in[7];
    const float* bf  = (const float*)d_in[8];
    const float* Wu  = (const float*)d_in[9];
    const float* bu  = (const float*)d_in[10];
    float* out = (float*)d_out;

    int* deg    = (int*)d_ws;                       // [N]
    int* offs   = deg + N_NODES;                    // [N]
    int* gcnt   = offs + N_NODES;                   // [256]
    int* elist  = gcnt + 256;                       // [E]
    float* ntf   = (float*)(elist + N_EDGES);       // [N*64]
    float* nfeat = ntf + (size_t)N_NODES * ADP;     // [N*64]
    float* fused = nfeat + (size_t)N_NODES * ADP;   // [N*64]
    // gbuf (196*12288 ints = 9.63MB) aliases nfeat (12.8MB): dead before k_down
    int* gbuf = (int*)nfeat;

    (void)hipMemsetAsync(gcnt, 0, 256 * sizeof(int), stream);

    k_bucket    <<<NB_BUCKET, 256, 0, stream>>>(ei, gcnt, gbuf);
    k_build     <<<     GRP, 512, 0, stream>>>(gcnt, gbuf, deg, offs, elist);
    k_gatherproj<<<   12500, 256, 0, stream>>>(ea, offs, deg, elist, Wt, bt, ntf);
    k_down      <<< NB_GEMM, 256, 0, stream>>>(x, Wd, bd, nfeat);
    k_fuse      <<< NB_GEMM, 256, 0, stream>>>(nfeat, ntf, Wf, bf, fused);
    k_up        <<< NB_GEMM, 256, 0, stream>>>(fused, x, Wu, bu, out);
}

// Round 9
// 458.152 us; speedup vs baseline: 2.5262x; 1.0070x over previous
//
#include <hip/hip_runtime.h>

#define N_NODES 50000
#define N_EDGES 1600000
#define IN_CH   256
#define ADP     64
#define EDGE_DIM 32
#define GRP     196     // ceil(50000/256) node groups
#define GCAP    12288   // per-group bucket capacity (mean 8163, sd ~90)
#define EPB_A   2048    // edges per block in k_bucket
#define NB_BUCKET ((N_EDGES + EPB_A - 1) / EPB_A)   // 782
#define NT16    (N_NODES / 16)                      // 3125 node tiles
#define NB_GEMM ((NT16 + 3) / 4)                    // 782
#define NB_GATHER (N_NODES / 8)                     // 6250 (2 nodes/wave)

typedef __fp16 h2 __attribute__((ext_vector_type(2)));
typedef _Float16 f16x8 __attribute__((ext_vector_type(8)));
typedef float f32x4 __attribute__((ext_vector_type(4)));

__device__ inline f16x8 cvt8(float4 a, float4 b) {
    union { f16x8 v; h2 h[4]; } r;
    r.h[0] = __builtin_amdgcn_cvt_pkrtz(a.x, a.y);
    r.h[1] = __builtin_amdgcn_cvt_pkrtz(a.z, a.w);
    r.h[2] = __builtin_amdgcn_cvt_pkrtz(b.x, b.y);
    r.h[3] = __builtin_amdgcn_cvt_pkrtz(b.z, b.w);
    return r.v;
}

// ---------------- K_A: coarse bucket by 256-node group (R3/R6-proven) --------
__global__ __launch_bounds__(256) void k_bucket(const int* __restrict__ ei_src,
                                                int* __restrict__ gcnt,
                                                int* __restrict__ gbuf) {
    __shared__ int cnt[GRP];
    __shared__ int cur[GRP];
    int t = threadIdx.x;
    if (t < GRP) cnt[t] = 0;
    __syncthreads();
    int base = blockIdx.x * EPB_A;
    int s[8];
    #pragma unroll
    for (int k = 0; k < 8; k++) {
        int e = base + k * 256 + t;
        int v = (e < N_EDGES) ? ei_src[e] : -1;
        s[k] = v;
        if (v >= 0) atomicAdd(&cnt[v >> 8], 1);
    }
    __syncthreads();
    if (t < GRP) cur[t] = atomicAdd(&gcnt[t], cnt[t]);
    __syncthreads();
    #pragma unroll
    for (int k = 0; k < 8; k++) {
        int v = s[k];
        if (v >= 0) {
            int e = base + k * 256 + t;
            int g = v >> 8;
            int slot = atomicAdd(&cur[g], 1);
            if (slot < GCAP)
                gbuf[g * GCAP + slot] = (e << 8) | (v & 255);
        }
    }
}

// ---------------- K_B: per-group deg/offs/elist build (R3/R6-proven) ---------
__global__ __launch_bounds__(512) void k_build(const int* __restrict__ gcnt,
                                               const int* __restrict__ gbuf,
                                               int* __restrict__ deg,
                                               int* __restrict__ offs,
                                               int* __restrict__ elist) {
    __shared__ int a[256], b[256], dcnt[256], cur[256];
    int t = threadIdx.x;
    int g = blockIdx.x;
    if (t < 256) a[t] = (t < GRP) ? min(gcnt[t], GCAP) : 0;
    __syncthreads();
    int* sp = a; int* dp = b;
    for (int o = 1; o < 256; o <<= 1) {
        if (t < 256) { int v2 = sp[t]; if (t >= o) v2 += sp[t - o]; dp[t] = v2; }
        __syncthreads();
        int* tmp = sp; sp = dp; dp = tmp;
    }
    int base = (g == 0) ? 0 : sp[g - 1];
    int sz = min(gcnt[g], GCAP);
    if (t < 256) dcnt[t] = 0;
    __syncthreads();
    const int* src = gbuf + (size_t)g * GCAP;
    for (int i = t; i < sz; i += 512) atomicAdd(&dcnt[src[i] & 255], 1);
    __syncthreads();
    if (t < 256) a[t] = dcnt[t];
    __syncthreads();
    sp = a; dp = b;
    for (int o = 1; o < 256; o <<= 1) {
        if (t < 256) { int v2 = sp[t]; if (t >= o) v2 += sp[t - o]; dp[t] = v2; }
        __syncthreads();
        int* tmp = sp; sp = dp; dp = tmp;
    }
    if (t < 256) {
        int v = dcnt[t];
        int pref = sp[t] - v;
        int n = g * 256 + t;
        if (n < N_NODES) { deg[n] = v; offs[n] = base + pref; }
        cur[t] = pref;
    }
    __syncthreads();
    for (int i = t; i < sz; i += 512) {
        int p = src[i];
        int slot = atomicAdd(&cur[p & 255], 1);
        elist[base + slot] = p >> 8;
    }
}

// ---------------- K3: gather + MFMA proj + mean, 2 nodes/wave ----------------
// 8 independent index loads -> 16 independent 32B payload loads in flight
// (2x R6's distinct rows/wave) -> 32 masked MFMAs. All elist reads clamped;
// er<d masks cover d==0 and clamped duplicates.
__global__ __launch_bounds__(256) void k_gatherproj(const float* __restrict__ ea,
                                                    const int* __restrict__ offs,
                                                    const int* __restrict__ deg,
                                                    const int* __restrict__ elist,
                                                    const float* __restrict__ Wt,
                                                    const float* __restrict__ bt,
                                                    float* __restrict__ ntf) {
    int t = threadIdx.x;
    int lane = t & 63, wv = t >> 6, col = lane & 15, q = lane >> 4;
    f16x8 bf[4];
    float bias[4];
    #pragma unroll
    for (int nt = 0; nt < 4; nt++) {
        const float4* wr = (const float4*)(Wt + (size_t)(nt * 16 + col) * EDGE_DIM + q * 8);
        bf[nt] = cvt8(wr[0], wr[1]);
        bias[nt] = bt[nt * 16 + col];
    }
    int nA = blockIdx.x * 8 + wv * 2;
    int nB = nA + 1;                      // NB_GATHER*8 == N_NODES: always in range
    int stA = offs[nA], dA = deg[nA];
    int stB = offs[nB], dB = deg[nB];
    const float4* ea4 = (const float4*)ea;
    f32x4 z = {0.f, 0.f, 0.f, 0.f};
    // 8 independent index loads (clamped; masks cover d==0)
    int idxA[4], idxB[4];
    #pragma unroll
    for (int c = 0; c < 4; c++) {
        int p = 16 * c + col;
        int pa = p < dA ? p : (dA > 0 ? dA - 1 : 0);
        int pb = p < dB ? p : (dB > 0 ? dB - 1 : 0);
        idxA[c] = elist[min(stA + pa, N_EDGES - 1)];
        idxB[c] = elist[min(stB + pb, N_EDGES - 1)];
    }
    // 16 independent 32B payload loads
    f16x8 afA[4], afB[4];
    #pragma unroll
    for (int c = 0; c < 4; c++) {
        const float4* pA = ea4 + (size_t)idxA[c] * 8 + q * 2;
        const float4* pB = ea4 + (size_t)idxB[c] * 8 + q * 2;
        float4 a0 = pA[0], a1 = pA[1];
        float4 b0 = pB[0], b1 = pB[1];
        afA[c] = cvt8(a0, a1);
        afB[c] = cvt8(b0, b1);
    }
    float sA0 = 0.f, sA1 = 0.f, sA2 = 0.f, sA3 = 0.f;
    float sB0 = 0.f, sB1 = 0.f, sB2 = 0.f, sB3 = 0.f;
    #pragma unroll
    for (int c = 0; c < 4; c++) {
        f32x4 dA0 = __builtin_amdgcn_mfma_f32_16x16x32_f16(afA[c], bf[0], z, 0, 0, 0);
        f32x4 dA1 = __builtin_amdgcn_mfma_f32_16x16x32_f16(afA[c], bf[1], z, 0, 0, 0);
        f32x4 dA2 = __builtin_amdgcn_mfma_f32_16x16x32_f16(afA[c], bf[2], z, 0, 0, 0);
        f32x4 dA3 = __builtin_amdgcn_mfma_f32_16x16x32_f16(afA[c], bf[3], z, 0, 0, 0);
        f32x4 dB0 = __builtin_amdgcn_mfma_f32_16x16x32_f16(afB[c], bf[0], z, 0, 0, 0);
        f32x4 dB1 = __builtin_amdgcn_mfma_f32_16x16x32_f16(afB[c], bf[1], z, 0, 0, 0);
        f32x4 dB2 = __builtin_amdgcn_mfma_f32_16x16x32_f16(afB[c], bf[2], z, 0, 0, 0);
        f32x4 dB3 = __builtin_amdgcn_mfma_f32_16x16x32_f16(afB[c], bf[3], z, 0, 0, 0);
        #pragma unroll
        for (int r = 0; r < 4; r++) {
            int er = 16 * c + q * 4 + r;
            bool okA = er < dA, okB = er < dB;
            sA0 += okA ? fmaxf(dA0[r] + bias[0], 0.f) : 0.f;
            sA1 += okA ? fmaxf(dA1[r] + bias[1], 0.f) : 0.f;
            sA2 += okA ? fmaxf(dA2[r] + bias[2], 0.f) : 0.f;
            sA3 += okA ? fmaxf(dA3[r] + bias[3], 0.f) : 0.f;
            sB0 += okB ? fmaxf(dB0[r] + bias[0], 0.f) : 0.f;
            sB1 += okB ? fmaxf(dB1[r] + bias[1], 0.f) : 0.f;
            sB2 += okB ? fmaxf(dB2[r] + bias[2], 0.f) : 0.f;
            sB3 += okB ? fmaxf(dB3[r] + bias[3], 0.f) : 0.f;
        }
    }
    // rare tails (P~4e-4): d > 64
    for (int base = 64; base < dA; base += 16) {
        int cnt = dA - base; if (cnt > 16) cnt = 16;
        int e = elist[min(stA + base + (col < cnt ? col : cnt - 1), N_EDGES - 1)];
        const float4* p = ea4 + (size_t)e * 8 + q * 2;
        float4 v0 = p[0], v1 = p[1];
        f16x8 af2 = cvt8(v0, v1);
        f32x4 d0 = __builtin_amdgcn_mfma_f32_16x16x32_f16(af2, bf[0], z, 0, 0, 0);
        f32x4 d1 = __builtin_amdgcn_mfma_f32_16x16x32_f16(af2, bf[1], z, 0, 0, 0);
        f32x4 d2 = __builtin_amdgcn_mfma_f32_16x16x32_f16(af2, bf[2], z, 0, 0, 0);
        f32x4 d3 = __builtin_amdgcn_mfma_f32_16x16x32_f16(af2, bf[3], z, 0, 0, 0);
        #pragma unroll
        for (int r = 0; r < 4; r++) {
            bool ok = (q * 4 + r) < cnt;
            sA0 += ok ? fmaxf(d0[r] + bias[0], 0.f) : 0.f;
            sA1 += ok ? fmaxf(d1[r] + bias[1], 0.f) : 0.f;
            sA2 += ok ? fmaxf(d2[r] + bias[2], 0.f) : 0.f;
            sA3 += ok ? fmaxf(d3[r] + bias[3], 0.f) : 0.f;
        }
    }
    for (int base = 64; base < dB; base += 16) {
        int cnt = dB - base; if (cnt > 16) cnt = 16;
        int e = elist[min(stB + base + (col < cnt ? col : cnt - 1), N_EDGES - 1)];
        const float4* p = ea4 + (size_t)e * 8 + q * 2;
        float4 v0 = p[0], v1 = p[1];
        f16x8 af2 = cvt8(v0, v1);
        f32x4 d0 = __builtin_amdgcn_mfma_f32_16x16x32_f16(af2, bf[0], z, 0, 0, 0);
        f32x4 d1 = __builtin_amdgcn_mfma_f32_16x16x32_f16(af2, bf[1], z, 0, 0, 0);
        f32x4 d2 = __builtin_amdgcn_mfma_f32_16x16x32_f16(af2, bf[2], z, 0, 0, 0);
        f32x4 d3 = __builtin_amdgcn_mfma_f32_16x16x32_f16(af2, bf[3], z, 0, 0, 0);
        #pragma unroll
        for (int r = 0; r < 4; r++) {
            bool ok = (q * 4 + r) < cnt;
            sB0 += ok ? fmaxf(d0[r] + bias[0], 0.f) : 0.f;
            sB1 += ok ? fmaxf(d1[r] + bias[1], 0.f) : 0.f;
            sB2 += ok ? fmaxf(d2[r] + bias[2], 0.f) : 0.f;
            sB3 += ok ? fmaxf(d3[r] + bias[3], 0.f) : 0.f;
        }
    }
    sA0 += __shfl_xor(sA0, 16, 64); sA0 += __shfl_xor(sA0, 32, 64);
    sA1 += __shfl_xor(sA1, 16, 64); sA1 += __shfl_xor(sA1, 32, 64);
    sA2 += __shfl_xor(sA2, 16, 64); sA2 += __shfl_xor(sA2, 32, 64);
    sA3 += __shfl_xor(sA3, 16, 64); sA3 += __shfl_xor(sA3, 32, 64);
    sB0 += __shfl_xor(sB0, 16, 64); sB0 += __shfl_xor(sB0, 32, 64);
    sB1 += __shfl_xor(sB1, 16, 64); sB1 += __shfl_xor(sB1, 32, 64);
    sB2 += __shfl_xor(sB2, 16, 64); sB2 += __shfl_xor(sB2, 32, 64);
    sB3 += __shfl_xor(sB3, 16, 64); sB3 += __shfl_xor(sB3, 32, 64);
    float resA = (q == 0) ? sA0 : (q == 1) ? sA1 : (q == 2) ? sA2 : sA3;
    float resB = (q == 0) ? sB0 : (q == 1) ? sB1 : (q == 2) ? sB2 : sB3;
    ntf[(size_t)nA * ADP + lane] = resA / fmaxf((float)dA, 1.f);
    ntf[(size_t)nB * ADP + lane] = resB / fmaxf((float)dB, 1.f);
}

// ---------------- K4: node_feat = relu(x @ W_down^T + b) via MFMA (R6) -------
__global__ __launch_bounds__(256) void k_down(const float* __restrict__ x,
                                              const float* __restrict__ Wd,
                                              const float* __restrict__ bd,
                                              float* __restrict__ nfeat) {
    __shared__ f16x8 wlds[8][4][64];   // [kc][nt][lane] = 32KB
    int t = threadIdx.x;
    int lane = t & 63, col = lane & 15, q = lane >> 4;
    for (int f = t; f < 8 * 4 * 64; f += 256) {
        int l = f & 63, ntk = f >> 6;
        int nt = ntk & 3, kc = ntk >> 2;
        const float4* wr = (const float4*)(Wd + (size_t)(nt * 16 + (l & 15)) * IN_CH
                                           + kc * 32 + (l >> 4) * 8);
        wlds[kc][nt][l] = cvt8(wr[0], wr[1]);
    }
    __syncthreads();
    int tile = blockIdx.x * 4 + (t >> 6);
    if (tile >= NT16) return;
    int n0 = tile * 16;
    float bias[4];
    #pragma unroll
    for (int nt = 0; nt < 4; nt++) bias[nt] = bd[nt * 16 + col];
    f32x4 z = {0.f, 0.f, 0.f, 0.f};
    f32x4 acc[4];
    #pragma unroll
    for (int nt = 0; nt < 4; nt++) acc[nt] = z;
    #pragma unroll
    for (int kc = 0; kc < 8; kc++) {
        const float4* xr = (const float4*)(x + (size_t)(n0 + col) * IN_CH + kc * 32 + q * 8);
        float4 v0 = xr[0], v1 = xr[1];
        f16x8 af = cvt8(v0, v1);
        #pragma unroll
        for (int nt = 0; nt < 4; nt++)
            acc[nt] = __builtin_amdgcn_mfma_f32_16x16x32_f16(af, wlds[kc][nt][lane], acc[nt], 0, 0, 0);
    }
    #pragma unroll
    for (int nt = 0; nt < 4; nt++)
        #pragma unroll
        for (int r = 0; r < 4; r++)
            nfeat[(size_t)(n0 + q * 4 + r) * ADP + nt * 16 + col] = fmaxf(acc[nt][r] + bias[nt], 0.f);
}

// ---------------- K5: fused = relu([nf|ntf] @ Wf^T + b) via MFMA (R6) --------
__global__ __launch_bounds__(256) void k_fuse(const float* __restrict__ nfeat,
                                              const float* __restrict__ ntf,
                                              const float* __restrict__ Wf,
                                              const float* __restrict__ bf_,
                                              float* __restrict__ fused) {
    __shared__ f16x8 wlds[4][4][64];   // 16KB
    int t = threadIdx.x;
    int lane = t & 63, col = lane & 15, q = lane >> 4;
    for (int f = t; f < 4 * 4 * 64; f += 256) {
        int l = f & 63, ntk = f >> 6;
        int nt = ntk & 3, kc = ntk >> 2;
        const float4* wr = (const float4*)(Wf + (size_t)(nt * 16 + (l & 15)) * (2 * ADP)
                                           + kc * 32 + (l >> 4) * 8);
        wlds[kc][nt][l] = cvt8(wr[0], wr[1]);
    }
    __syncthreads();
    int tile = blockIdx.x * 4 + (t >> 6);
    if (tile >= NT16) return;
    int n0 = tile * 16;
    float bias[4];
    #pragma unroll
    for (int nt = 0; nt < 4; nt++) bias[nt] = bf_[nt * 16 + col];
    f32x4 z = {0.f, 0.f, 0.f, 0.f};
    f32x4 acc[4];
    #pragma unroll
    for (int nt = 0; nt < 4; nt++) acc[nt] = z;
    #pragma unroll
    for (int kc = 0; kc < 4; kc++) {
        const float* srcb = (kc < 2) ? nfeat : ntf;
        int ko = (kc & 1) * 32;
        const float4* xr = (const float4*)(srcb + (size_t)(n0 + col) * ADP + ko + q * 8);
        float4 v0 = xr[0], v1 = xr[1];
        f16x8 af = cvt8(v0, v1);
        #pragma unroll
        for (int nt = 0; nt < 4; nt++)
            acc[nt] = __builtin_amdgcn_mfma_f32_16x16x32_f16(af, wlds[kc][nt][lane], acc[nt], 0, 0, 0);
    }
    #pragma unroll
    for (int nt = 0; nt < 4; nt++)
        #pragma unroll
        for (int r = 0; r < 4; r++)
            fused[(size_t)(n0 + q * 4 + r) * ADP + nt * 16 + col] = fmaxf(acc[nt][r] + bias[nt], 0.f);
}

// ---------------- K6: out = x + fused @ Wu^T + bu via MFMA (R6) --------------
__global__ __launch_bounds__(256) void k_up(const float* __restrict__ fused,
                                            const float* __restrict__ x,
                                            const float* __restrict__ Wu,
                                            const float* __restrict__ bu,
                                            float* __restrict__ out) {
    __shared__ f16x8 wlds[2][16][64];   // 32KB
    int t = threadIdx.x;
    int lane = t & 63, col = lane & 15, q = lane >> 4;
    for (int f = t; f < 2 * 16 * 64; f += 256) {
        int l = f & 63, ntk = f >> 6;
        int nt = ntk & 15, kc = ntk >> 4;
        const float4* wr = (const float4*)(Wu + (size_t)(nt * 16 + (l & 15)) * ADP
                                           + kc * 32 + (l >> 4) * 8);
        wlds[kc][nt][l] = cvt8(wr[0], wr[1]);
    }
    __syncthreads();
    int tile = blockIdx.x * 4 + (t >> 6);
    if (tile >= NT16) return;
    int n0 = tile * 16;
    f32x4 z = {0.f, 0.f, 0.f, 0.f};
    f32x4 acc[16];
    #pragma unroll
    for (int nt = 0; nt < 16; nt++) acc[nt] = z;
    #pragma unroll
    for (int kc = 0; kc < 2; kc++) {
        const float4* xr = (const float4*)(fused + (size_t)(n0 + col) * ADP + kc * 32 + q * 8);
        float4 v0 = xr[0], v1 = xr[1];
        f16x8 af = cvt8(v0, v1);
        #pragma unroll
        for (int nt = 0; nt < 16; nt++)
            acc[nt] = __builtin_amdgcn_mfma_f32_16x16x32_f16(af, wlds[kc][nt][lane], acc[nt], 0, 0, 0);
    }
    #pragma unroll
    for (int nt = 0; nt < 16; nt++) {
        float b = bu[nt * 16 + col];
        #pragma unroll
        for (int r = 0; r < 4; r++) {
            size_t idx = (size_t)(n0 + q * 4 + r) * IN_CH + nt * 16 + col;
            out[idx] = x[idx] + acc[nt][r] + b;
        }
    }
}

extern "C" void kernel_launch(void* const* d_in, const int* in_sizes, int n_in,
                              void* d_out, int out_size, void* d_ws, size_t ws_size,
                              hipStream_t stream) {
    const float* x   = (const float*)d_in[0];
    const int*   ei  = (const int*)d_in[1];     // [2, E]; row 0 = src
    const float* ea  = (const float*)d_in[2];
    const float* Wd  = (const float*)d_in[3];
    const float* bd  = (const float*)d_in[4];
    const float* Wt  = (const float*)d_in[5];
    const float* bt  = (const float*)d_in[6];
    const float* Wf  = (const float*)d_in[7];
    const float* bf  = (const float*)d_in[8];
    const float* Wu  = (const float*)d_in[9];
    const float* bu  = (const float*)d_in[10];
    float* out = (float*)d_out;

    int* deg    = (int*)d_ws;                       // [N]
    int* offs   = deg + N_NODES;                    // [N]
    int* gcnt   = offs + N_NODES;                   // [256]
    int* elist  = gcnt + 256;                       // [E]
    float* ntf   = (float*)(elist + N_EDGES);       // [N*64]
    float* nfeat = ntf + (size_t)N_NODES * ADP;     // [N*64]
    float* fused = nfeat + (size_t)N_NODES * ADP;   // [N*64]
    // gbuf (196*12288 ints = 9.63MB) aliases nfeat (12.8MB): dead before k_down
    int* gbuf = (int*)nfeat;

    (void)hipMemsetAsync(gcnt, 0, 256 * sizeof(int), stream);

    k_bucket    <<<NB_BUCKET, 256, 0, stream>>>(ei, gcnt, gbuf);
    k_build     <<<     GRP, 512, 0, stream>>>(gcnt, gbuf, deg, offs, elist);
    k_gatherproj<<<NB_GATHER, 256, 0, stream>>>(ea, offs, deg, elist, Wt, bt, ntf);
    k_down      <<< NB_GEMM, 256, 0, stream>>>(x, Wd, bd, nfeat);
    k_fuse      <<< NB_GEMM, 256, 0, stream>>>(nfeat, ntf, Wf, bf, fused);
    k_up        <<< NB_GEMM, 256, 0, stream>>>(fused, x, Wu, bu, out);
}